// Round 1
// 728.121 us; speedup vs baseline: 1.0150x; 1.0150x over previous
//
#include <hip/hip_runtime.h>

#define DIM 64
#define CAP 128          // per-node bucket capacity; Poisson(mean=32) max ~60. Multiple of 4.
#define OVF_CAP 65536

typedef float v4f __attribute__((ext_vector_type(4)));
typedef int   v4i __attribute__((ext_vector_type(4)));
typedef int   v2i __attribute__((ext_vector_type(2)));

__device__ __forceinline__ float wave_reduce_sum(float v) {
    #pragma unroll
    for (int off = 32; off > 0; off >>= 1)
        v += __shfl_xor(v, off, 64);
    return v;
}

// Phase A: bucket (edge_id, src[edge]) pairs by destination node.
// src[e] is COALESCED here (e is thread-linear) -- fusing it into the bucket
// removes one level of the dependent gather chain from node_kernel.
__global__ __launch_bounds__(256) void bucket_kernel(
    const int* __restrict__ dst,
    const int* __restrict__ src,
    int* __restrict__ cnt, int* __restrict__ ovf_cnt,
    int* __restrict__ ovf_list, v2i* __restrict__ list2,
    int n_edges)
{
    const int t0   = blockIdx.x * 256 + threadIdx.x;
    const int base = t0 * 4;
    if (base >= n_edges) return;

    if (base + 4 <= n_edges) {
        // 16B coalesced loads of 4 dst + 4 src
        const v4i d4 = *(const v4i*)(dst + base);
        const v4i s4 = *(const v4i*)(src + base);
        #pragma unroll
        for (int k = 0; k < 4; ++k) {
            const int e = base + k;
            const int t = (k == 0) ? d4.x : (k == 1) ? d4.y : (k == 2) ? d4.z : d4.w;
            const int s = (k == 0) ? s4.x : (k == 1) ? s4.y : (k == 2) ? s4.z : s4.w;
            const int pos = atomicAdd(&cnt[t], 1);
            if (pos < CAP) {
                list2[(size_t)t * CAP + pos] = (v2i){e, s};
            } else {
                const int op = atomicAdd(ovf_cnt, 1);
                if (op < OVF_CAP) ovf_list[op] = e;
            }
        }
    } else {
        for (int e = base; e < n_edges; ++e) {
            const int t = dst[e];
            const int s = src[e];
            const int pos = atomicAdd(&cnt[t], 1);
            if (pos < CAP) {
                list2[(size_t)t * CAP + pos] = (v2i){e, s};
            } else {
                const int op = atomicAdd(ovf_cnt, 1);
                if (op < OVF_CAP) ovf_list[op] = e;
            }
        }
    }
}

// Phase B: one wave per node. 4 edges per iteration: 16 lanes per edge,
// each lane holds a v4f (16 lanes x 4 = 64 dims). Zero f32 atomics.
// All (e, src) pairs for the node are loaded up-front into registers
// (one coalesced 8B/lane load), so the inner loop has NO dependent
// scalar loads -- only two independent 16B gathers per edge.
__global__ __launch_bounds__(256) void node_kernel(
    const v4f* __restrict__ node_emb4,   // [N, 16] v4f
    const v4f* __restrict__ edge_emb4,   // [E, 16] v4f
    const int* __restrict__ cnt,
    const v2i* __restrict__ list2,       // [N, CAP] (edge_id, src)
    v4f*   __restrict__ h4,              // [N, 16] v4f
    float* __restrict__ dr,              // [E]
    int n_nodes)
{
    const int v    = (blockIdx.x * 256 + threadIdx.x) >> 6;
    const int lane = threadIdx.x & 63;
    const int g    = lane >> 4;   // which of the 4 edges in this batch
    const int p    = lane & 15;   // v4f slot within the 64-dim row
    if (v >= n_nodes) return;

    int deg = cnt[v]; if (deg > CAP) deg = CAP;
    const v2i* lst = list2 + (size_t)v * CAP;

    const v4f tl = node_emb4[(size_t)v * 16 + p];   // tail row, loop-invariant

    v4f acc = (v4f){0.f, 0.f, 0.f, 0.f};

    if (deg > 0) {
        // Up-front register staging of the whole adjacency list.
        // Lanes >= deg read lst[0], which is always written when deg >= 1.
        v2i es0 = lst[(lane < deg) ? lane : 0];
        v2i es1 = (v2i){0, 0};
        if (deg > 64) es1 = lst[((64 + lane) < deg) ? (64 + lane) : 0];

        #pragma unroll 2
        for (int i = 0; i < deg; i += 4) {
            int idx = i + g;
            const bool active = idx < deg;
            if (!active) idx = i;            // clamp to a valid, same-half index
            int e, s;
            if (i < 64) {                    // wave-uniform: i multiple of 4
                e = __shfl(es0.x, idx, 64);
                s = __shfl(es0.y, idx, 64);
            } else {
                e = __shfl(es1.x, idx - 64, 64);
                s = __shfl(es1.y, idx - 64, 64);
            }

            const v4f hd = node_emb4[(size_t)s * 16 + p];
            const v4f rl = __builtin_nontemporal_load(&edge_emb4[(size_t)e * 16 + p]);

            v4f pr = hd * rl;

            float dv = pr.x * tl.x + pr.y * tl.y + pr.z * tl.z + pr.w * tl.w;
            // reduce across the 16 lanes of this edge-group (DPP, no LDS)
            dv += __shfl_xor(dv, 1, 64);
            dv += __shfl_xor(dv, 2, 64);
            dv += __shfl_xor(dv, 4, 64);
            dv += __shfl_xor(dv, 8, 64);

            if (active) {
                if (p == 0) __builtin_nontemporal_store(dv, &dr[e]);
                const float sig = 1.f / (1.f + __expf(-dv));
                acc += sig * pr;
            }
        }
    }

    // combine the 4 edge-groups' partial accumulators (lanes with same p)
    acc.x += __shfl_xor(acc.x, 16, 64); acc.y += __shfl_xor(acc.y, 16, 64);
    acc.z += __shfl_xor(acc.z, 16, 64); acc.w += __shfl_xor(acc.w, 16, 64);
    acc.x += __shfl_xor(acc.x, 32, 64); acc.y += __shfl_xor(acc.y, 32, 64);
    acc.z += __shfl_xor(acc.z, 32, 64); acc.w += __shfl_xor(acc.w, 32, 64);

    if (g == 0) __builtin_nontemporal_store(acc, &h4[(size_t)v * 16 + p]);
}

// Phase C: overflow edges (expected count: 0) via the atomic path.
__global__ __launch_bounds__(256) void overflow_kernel(
    const float* __restrict__ node_emb,
    const float* __restrict__ edge_emb,
    const int*   __restrict__ src,
    const int*   __restrict__ dst,
    const int*   __restrict__ ovf_cnt,
    const int*   __restrict__ ovf_list,
    float* __restrict__ h,
    float* __restrict__ dr)
{
    int n = *ovf_cnt; if (n > OVF_CAP) n = OVF_CAP;
    const int wave = (blockIdx.x * 256 + threadIdx.x) >> 6;
    const int d = threadIdx.x & 63;
    const int nwaves = gridDim.x * 4;
    for (int i = wave; i < n; i += nwaves) {
        const int e = ovf_list[i];
        const int s = src[e], t = dst[e];
        const float hd = node_emb[(size_t)s * DIM + d];
        const float rl = edge_emb[(size_t)e * DIM + d];
        const float tl = node_emb[(size_t)t * DIM + d];
        const float p = hd * rl;
        const float v = wave_reduce_sum(p * tl);
        if (d == 0) dr[e] = v;
        unsafeAtomicAdd(&h[(size_t)t * DIM + d], p / (1.f + __expf(-v)));
    }
}

// Fallback (ws too small): single-pass atomic kernel.
__global__ __launch_bounds__(256) void edge_atomic_kernel(
    const float* __restrict__ node_emb,
    const float* __restrict__ edge_emb,
    const int*   __restrict__ src,
    const int*   __restrict__ dst,
    float* __restrict__ h,
    float* __restrict__ dr,
    int n_edges)
{
    const int e = (int)((blockIdx.x * (unsigned)blockDim.x + threadIdx.x) >> 6);
    const int d = threadIdx.x & 63;
    if (e >= n_edges) return;
    const int s = src[e], t = dst[e];
    const float hd = node_emb[(size_t)s * DIM + d];
    const float rl = edge_emb[(size_t)e * DIM + d];
    const float tl = node_emb[(size_t)t * DIM + d];
    const float p = hd * rl;
    const float v = wave_reduce_sum(p * tl);
    if (d == 0) dr[e] = v;
    unsafeAtomicAdd(&h[(size_t)t * DIM + d], p / (1.f + __expf(-v)));
}

extern "C" void kernel_launch(void* const* d_in, const int* in_sizes, int n_in,
                              void* d_out, int out_size, void* d_ws, size_t ws_size,
                              hipStream_t stream) {
    const float* node_emb = (const float*)d_in[0];
    const float* edge_emb = (const float*)d_in[1];
    const int*   src      = (const int*)d_in[2];
    const int*   dst      = (const int*)d_in[3];

    const int n_nodes = in_sizes[0] / DIM;
    const int n_edges = in_sizes[2];

    float* h  = (float*)d_out;                 // [n_nodes, DIM]
    float* dr = h + (size_t)n_nodes * DIM;     // [n_edges]

    // Workspace: [cnt n_nodes][ovf_cnt 1][pad 63][ovf_list OVF_CAP] (ints)
    //            then [list2 n_nodes*CAP] (int2, 8B each)
    const size_t hdr_ints = (size_t)n_nodes + 64 + OVF_CAP;
    const size_t need = hdr_ints * sizeof(int) + (size_t)n_nodes * CAP * sizeof(v2i);

    if (ws_size < need) {
        (void)hipMemsetAsync(h, 0, (size_t)n_nodes * DIM * sizeof(float), stream);
        edge_atomic_kernel<<<(n_edges + 3) / 4, 256, 0, stream>>>(
            node_emb, edge_emb, src, dst, h, dr, n_edges);
        return;
    }

    int* cnt      = (int*)d_ws;
    int* ovf_cnt  = cnt + n_nodes;
    int* ovf_list = cnt + n_nodes + 64;
    v2i* list2    = (v2i*)(cnt + hdr_ints);    // 8B-aligned: hdr_ints*4 % 8 == 0

    (void)hipMemsetAsync(cnt, 0, (size_t)(n_nodes + 64) * sizeof(int), stream);

    const int bthreads = (n_edges + 3) / 4;
    bucket_kernel<<<(bthreads + 255) / 256, 256, 0, stream>>>(
        dst, src, cnt, ovf_cnt, ovf_list, list2, n_edges);

    node_kernel<<<(n_nodes * 64 + 255) / 256, 256, 0, stream>>>(
        (const v4f*)node_emb, (const v4f*)edge_emb, cnt, list2,
        (v4f*)h, dr, n_nodes);

    overflow_kernel<<<64, 256, 0, stream>>>(
        node_emb, edge_emb, src, dst, ovf_cnt, ovf_list, h, dr);
}

// Round 3
// 722.404 us; speedup vs baseline: 1.0231x; 1.0079x over previous
//
#include <hip/hip_runtime.h>

#define DIM 64
#define CAP 64           // per-node bucket capacity; Poisson(mean=32), P(deg>64)~1e-7 -> overflow path
#define OVF_CAP 65536

typedef float v4f __attribute__((ext_vector_type(4)));
typedef int   v4i __attribute__((ext_vector_type(4)));
typedef int   v2i __attribute__((ext_vector_type(2)));

__device__ __forceinline__ float wave_reduce_sum(float v) {
    #pragma unroll
    for (int off = 32; off > 0; off >>= 1)
        v += __shfl_xor(v, off, 64);
    return v;
}

// Phase A: bucket (edge_id, src[edge]) pairs by destination node.
// src[e] is COALESCED here (e is thread-linear) -- fusing it into the bucket
// removes one level of the dependent gather chain from node_kernel.
__global__ __launch_bounds__(256) void bucket_kernel(
    const int* __restrict__ dst,
    const int* __restrict__ src,
    int* __restrict__ cnt, int* __restrict__ ovf_cnt,
    int* __restrict__ ovf_list, v2i* __restrict__ list2,
    int n_edges)
{
    const int t0   = blockIdx.x * 256 + threadIdx.x;
    const int base = t0 * 4;
    if (base >= n_edges) return;

    if (base + 4 <= n_edges) {
        // 16B coalesced loads of 4 dst + 4 src
        const v4i d4 = *(const v4i*)(dst + base);
        const v4i s4 = *(const v4i*)(src + base);
        #pragma unroll
        for (int k = 0; k < 4; ++k) {
            const int e = base + k;
            const int t = (k == 0) ? d4.x : (k == 1) ? d4.y : (k == 2) ? d4.z : d4.w;
            const int s = (k == 0) ? s4.x : (k == 1) ? s4.y : (k == 2) ? s4.z : s4.w;
            const int pos = atomicAdd(&cnt[t], 1);
            if (pos < CAP) {
                list2[(size_t)t * CAP + pos] = (v2i){e, s};
            } else {
                const int op = atomicAdd(ovf_cnt, 1);
                if (op < OVF_CAP) ovf_list[op] = e;
            }
        }
    } else {
        for (int e = base; e < n_edges; ++e) {
            const int t = dst[e];
            const int s = src[e];
            const int pos = atomicAdd(&cnt[t], 1);
            if (pos < CAP) {
                list2[(size_t)t * CAP + pos] = (v2i){e, s};
            } else {
                const int op = atomicAdd(ovf_cnt, 1);
                if (op < OVF_CAP) ovf_list[op] = e;
            }
        }
    }
}

// Phase B: persistent grid-stride waves over nodes. 4 edges per iteration:
// 16 lanes per edge, each lane holds a v4f (16 lanes x 4 = 64 dims).
// Zero f32 atomics. The node's whole adjacency list (CAP=64 <= one entry
// per lane) is staged into registers with a single coalesced 8B/lane load,
// so the inner loop has NO dependent scalar loads -- only two independent
// 16B gathers per edge. Grid-stride removes block-granularity tail waste
// (E[max of 4 Poisson(32)] ~ 41 vs mean 32).
__global__ __launch_bounds__(256) void node_kernel(
    const v4f* __restrict__ node_emb4,   // [N, 16] v4f
    const v4f* __restrict__ edge_emb4,   // [E, 16] v4f
    const int* __restrict__ cnt,
    const v2i* __restrict__ list2,       // [N, CAP] (edge_id, src)
    v4f*   __restrict__ h4,              // [N, 16] v4f
    float* __restrict__ dr,              // [E]
    int n_nodes)
{
    const int wid    = (blockIdx.x * 256 + threadIdx.x) >> 6;
    const int nwaves = (gridDim.x * 256) >> 6;
    const int lane = threadIdx.x & 63;
    const int g    = lane >> 4;   // which of the 4 edges in this batch
    const int p    = lane & 15;   // v4f slot within the 64-dim row

    for (int v = wid; v < n_nodes; v += nwaves) {
        int deg = cnt[v]; if (deg > CAP) deg = CAP;
        const v2i* lst = list2 + (size_t)v * CAP;

        const v4f tl = node_emb4[(size_t)v * 16 + p];   // tail row, loop-invariant

        v4f acc = (v4f){0.f, 0.f, 0.f, 0.f};

        if (deg > 0) {
            // Stage the whole adjacency list into one register/lane.
            // Lanes >= deg read lst[0], which is always written when deg >= 1.
            const v2i es = lst[(lane < deg) ? lane : 0];

            #pragma unroll 2
            for (int i = 0; i < deg; i += 4) {
                int idx = i + g;
                const bool active = idx < deg;
                if (!active) idx = i;            // clamp to a valid index
                const int e = __shfl(es.x, idx, 64);
                const int s = __shfl(es.y, idx, 64);

                const v4f hd = node_emb4[(size_t)s * 16 + p];
                const v4f rl = __builtin_nontemporal_load(&edge_emb4[(size_t)e * 16 + p]);

                v4f pr = hd * rl;

                float dv = pr.x * tl.x + pr.y * tl.y + pr.z * tl.z + pr.w * tl.w;
                // reduce across the 16 lanes of this edge-group (DPP, no LDS)
                dv += __shfl_xor(dv, 1, 64);
                dv += __shfl_xor(dv, 2, 64);
                dv += __shfl_xor(dv, 4, 64);
                dv += __shfl_xor(dv, 8, 64);

                if (active) {
                    if (p == 0) __builtin_nontemporal_store(dv, &dr[e]);
                    const float sig = 1.f / (1.f + __expf(-dv));
                    acc += sig * pr;
                }
            }
        }

        // combine the 4 edge-groups' partial accumulators (lanes with same p)
        acc.x += __shfl_xor(acc.x, 16, 64); acc.y += __shfl_xor(acc.y, 16, 64);
        acc.z += __shfl_xor(acc.z, 16, 64); acc.w += __shfl_xor(acc.w, 16, 64);
        acc.x += __shfl_xor(acc.x, 32, 64); acc.y += __shfl_xor(acc.y, 32, 64);
        acc.z += __shfl_xor(acc.z, 32, 64); acc.w += __shfl_xor(acc.w, 32, 64);

        if (g == 0) __builtin_nontemporal_store(acc, &h4[(size_t)v * 16 + p]);
    }
}

// Phase C: overflow edges (expected count: ~0) via the atomic path.
__global__ __launch_bounds__(256) void overflow_kernel(
    const float* __restrict__ node_emb,
    const float* __restrict__ edge_emb,
    const int*   __restrict__ src,
    const int*   __restrict__ dst,
    const int*   __restrict__ ovf_cnt,
    const int*   __restrict__ ovf_list,
    float* __restrict__ h,
    float* __restrict__ dr)
{
    int n = *ovf_cnt; if (n > OVF_CAP) n = OVF_CAP;
    const int wave = (blockIdx.x * 256 + threadIdx.x) >> 6;
    const int d = threadIdx.x & 63;
    const int nwaves = gridDim.x * 4;
    for (int i = wave; i < n; i += nwaves) {
        const int e = ovf_list[i];
        const int s = src[e], t = dst[e];
        const float hd = node_emb[(size_t)s * DIM + d];
        const float rl = edge_emb[(size_t)e * DIM + d];
        const float tl = node_emb[(size_t)t * DIM + d];
        const float p = hd * rl;
        const float v = wave_reduce_sum(p * tl);
        if (d == 0) dr[e] = v;
        unsafeAtomicAdd(&h[(size_t)t * DIM + d], p / (1.f + __expf(-v)));
    }
}

// Fallback (ws too small): single-pass atomic kernel.
__global__ __launch_bounds__(256) void edge_atomic_kernel(
    const float* __restrict__ node_emb,
    const float* __restrict__ edge_emb,
    const int*   __restrict__ src,
    const int*   __restrict__ dst,
    float* __restrict__ h,
    float* __restrict__ dr,
    int n_edges)
{
    const int e = (int)((blockIdx.x * (unsigned)blockDim.x + threadIdx.x) >> 6);
    const int d = threadIdx.x & 63;
    if (e >= n_edges) return;
    const int s = src[e], t = dst[e];
    const float hd = node_emb[(size_t)s * DIM + d];
    const float rl = edge_emb[(size_t)e * DIM + d];
    const float tl = node_emb[(size_t)t * DIM + d];
    const float p = hd * rl;
    const float v = wave_reduce_sum(p * tl);
    if (d == 0) dr[e] = v;
    unsafeAtomicAdd(&h[(size_t)t * DIM + d], p / (1.f + __expf(-v)));
}

extern "C" void kernel_launch(void* const* d_in, const int* in_sizes, int n_in,
                              void* d_out, int out_size, void* d_ws, size_t ws_size,
                              hipStream_t stream) {
    const float* node_emb = (const float*)d_in[0];
    const float* edge_emb = (const float*)d_in[1];
    const int*   src      = (const int*)d_in[2];
    const int*   dst      = (const int*)d_in[3];

    const int n_nodes = in_sizes[0] / DIM;
    const int n_edges = in_sizes[2];

    float* h  = (float*)d_out;                 // [n_nodes, DIM]
    float* dr = h + (size_t)n_nodes * DIM;     // [n_edges]

    // Workspace: [cnt n_nodes][ovf_cnt 1][pad 63][ovf_list OVF_CAP] (ints)
    //            then [list2 n_nodes*CAP] (int2, 8B each)
    const size_t hdr_ints = (size_t)n_nodes + 64 + OVF_CAP;
    const size_t need = hdr_ints * sizeof(int) + (size_t)n_nodes * CAP * sizeof(v2i);

    if (ws_size < need) {
        (void)hipMemsetAsync(h, 0, (size_t)n_nodes * DIM * sizeof(float), stream);
        edge_atomic_kernel<<<(n_edges + 3) / 4, 256, 0, stream>>>(
            node_emb, edge_emb, src, dst, h, dr, n_edges);
        return;
    }

    int* cnt      = (int*)d_ws;
    int* ovf_cnt  = cnt + n_nodes;
    int* ovf_list = cnt + n_nodes + 64;
    v2i* list2    = (v2i*)(cnt + hdr_ints);    // 8B-aligned: hdr_ints*4 % 8 == 0

    (void)hipMemsetAsync(cnt, 0, (size_t)(n_nodes + 64) * sizeof(int), stream);

    const int bthreads = (n_edges + 3) / 4;
    bucket_kernel<<<(bthreads + 255) / 256, 256, 0, stream>>>(
        dst, src, cnt, ovf_cnt, ovf_list, list2, n_edges);

    // Persistent grid-stride: 2048 blocks = 8192 waves over 50K nodes.
    node_kernel<<<2048, 256, 0, stream>>>(
        (const v4f*)node_emb, (const v4f*)edge_emb, cnt, list2,
        (v4f*)h, dr, n_nodes);

    overflow_kernel<<<64, 256, 0, stream>>>(
        node_emb, edge_emb, src, dst, ovf_cnt, ovf_list, h, dr);
}